// Round 10
// baseline (125.140 us; speedup 1.0000x reference)
//
#include <hip/hip_runtime.h>
#include <hip/hip_bf16.h>

#define HID   64
#define BLOCK 512    // 8 waves
#define GPB   8      // 64-token tiles per block -> 512 tokens/block -> 2048 blocks
#define NBUF  4      // quad buffer: reuse distance 3 -> ONE barrier per tile

typedef short short8 __attribute__((ext_vector_type(8)));
typedef float floatx4 __attribute__((ext_vector_type(4)));

__device__ __forceinline__ short8 cvt8f(float4 f0, float4 f1) {
    union { __hip_bfloat162 h[4]; short8 s; } r;
    r.h[0] = __float22bfloat162_rn(make_float2(f0.x, f0.y));
    r.h[1] = __float22bfloat162_rn(make_float2(f0.z, f0.w));
    r.h[2] = __float22bfloat162_rn(make_float2(f1.x, f1.y));
    r.h[3] = __float22bfloat162_rn(make_float2(f1.z, f1.w));
    return r.s;
}

__device__ __forceinline__ void gload_lds16(const float* g, float* l) {
    __builtin_amdgcn_global_load_lds(
        (const __attribute__((address_space(1))) void*)g,
        (__attribute__((address_space(3))) void*)l, 16, 0, 0);
}

#define SB __builtin_amdgcn_sched_barrier(0)

// Tile = 64 tokens = 16 chunks of 256 floats. Chunk c = mt*4 + kc*2 + hf holds,
// at 16B slot `lane`, x[orig + mt*16 + r15][kg*8 + kc*32 + hf*4 .. +4)
// (rule 21: pre-swizzled global src, linear LDS dest).
// Wave w stages chunks 2w, 2w+1  (mt = w>>1, kc = w&1, hf = 0/1): 2 KB/wave.
#define STAGE(g) do {                                                             \
    const long orig_ = blk0 + (g) * 64;                                           \
    const float* s0_ = x + (orig_ + (wave >> 1) * 16 + r15) * HID                 \
                         + kg * 8 + (wave & 1) * 32;                              \
    gload_lds16(s0_,     &sbuf[(g) & 3][(wave * 2 + 0) * 256]);                   \
    gload_lds16(s0_ + 4, &sbuf[(g) & 3][(wave * 2 + 1) * 256]);                   \
    } while (0)

// mod loads for this wave's two token groups (mt = mh, mh+1); ride vmcnt queue.
#define MODL(g) do {                                                              \
    const long orig_ = blk0 + (g) * 64;                                           \
    mv[g][0] = mod[orig_ + (mh + 0) * 16 + r15];                                  \
    mv[g][1] = mod[orig_ + (mh + 1) * 16 + r15];                                  \
    } while (0)

// Wave computes its 16 cols (cg*16..) x 32 tokens (mt = mh, mh+1).
#define COMPUTE(g) do {                                                           \
    const long orig_ = blk0 + (g) * 64;                                           \
    _Pragma("unroll")                                                             \
    for (int mtl = 0; mtl < 2; ++mtl) {                                           \
        const int mt_ = mh + mtl;                                                 \
        const float4 q0 = *(const float4*)&sbuf[(g)&3][(mt_*4+0)*256 + lane*4];   \
        const float4 q1 = *(const float4*)&sbuf[(g)&3][(mt_*4+1)*256 + lane*4];   \
        const float4 q2 = *(const float4*)&sbuf[(g)&3][(mt_*4+2)*256 + lane*4];   \
        const float4 q3 = *(const float4*)&sbuf[(g)&3][(mt_*4+3)*256 + lane*4];   \
        const short8 xb0 = cvt8f(q0, q1);                                         \
        const short8 xb1 = cvt8f(q2, q3);                                         \
        floatx4 a0 = {0.f,0.f,0.f,0.f}, a1 = {0.f,0.f,0.f,0.f},                   \
                a2 = {0.f,0.f,0.f,0.f};                                           \
        a0 = __builtin_amdgcn_mfma_f32_16x16x32_bf16(wa[0][0], xb0, a0,0,0,0);    \
        a0 = __builtin_amdgcn_mfma_f32_16x16x32_bf16(wa[0][1], xb1, a0,0,0,0);    \
        a1 = __builtin_amdgcn_mfma_f32_16x16x32_bf16(wa[1][0], xb0, a1,0,0,0);    \
        a1 = __builtin_amdgcn_mfma_f32_16x16x32_bf16(wa[1][1], xb1, a1,0,0,0);    \
        a2 = __builtin_amdgcn_mfma_f32_16x16x32_bf16(wa[2][0], xb0, a2,0,0,0);    \
        a2 = __builtin_amdgcn_mfma_f32_16x16x32_bf16(wa[2][1], xb1, a2,0,0,0);    \
        const int m_ = mv[g][mtl];                                                \
        const floatx4 v_ = (m_ == 0) ? a0 : ((m_ == 1) ? a1 : a2);                \
        *(floatx4*)(out + (orig_ + mt_ * 16 + r15) * HID + cg * 16 + kg * 4)      \
            = v_;                                                                 \
    } } while (0)

#define WAITV(N) asm volatile("s_waitcnt vmcnt(" #N ")" ::: "memory")

// One barrier per tile. Order: WAIT(stage g done) -> barrier (makes all waves'
// stage(g) visible AND proves all finished COMPUTE(g-1)) -> COMPUTE(g) ->
// STAGE(g+3) into buf((g-1)&3), now provably free.
#define ITER(g, K)                                                                \
    WAITV(K); __builtin_amdgcn_s_barrier(); SB;                                   \
    COMPUTE(g); SB;                                                               \
    STAGE((g) + 3); SB; MODL((g) + 3); SB;

#define ITER_TAIL(g, K)                                                           \
    WAITV(K); __builtin_amdgcn_s_barrier(); SB;                                   \
    COMPUTE(g); SB;

__global__ __launch_bounds__(BLOCK) void moe_qb(
    const float* __restrict__ x,
    const float* __restrict__ W,
    const int* __restrict__ mod,
    float* __restrict__ out)
{
    __shared__ float sbuf[NBUF][16 * 256];   // 4 x 16 KB = 64 KB

    const int tid  = threadIdx.x;
    const int wave = tid >> 6;               // 0..7
    const int lane = tid & 63;
    const int r15  = lane & 15;              // token within 16-group / MFMA col
    const int kg   = lane >> 4;              // k-group 0..3
    const int cg   = wave & 3;               // col-group: cols cg*16..cg*16+15
    const int mh   = (wave >> 2) * 2;        // first mt of this wave's token half

    const long blk0 = (long)blockIdx.x * (64 * GPB);

    int mv[GPB][2];                          // static-indexed via unrolled macros

    // ---- prologue: W fragments first (their loads drain via cvt use) ----
    short8 wa[3][2];
#pragma unroll
    for (int mm = 0; mm < 3; ++mm) {
        const float* wp = W + mm * 4096 + (cg * 16 + r15) * HID + kg * 8;
        wa[mm][0] = cvt8f(*(const float4*)wp,        *(const float4*)(wp + 4));
        wa[mm][1] = cvt8f(*(const float4*)(wp + 32), *(const float4*)(wp + 36));
    }
    SB;

    // queue: s0(2) m0(2) s1(2) m1(2) s2(2) m2(2)
    STAGE(0); SB; MODL(0); SB;
    STAGE(1); SB; MODL(1); SB;
    STAGE(2); SB; MODL(2); SB;

    // exact counts (ops younger than tile g's last mod load):
    ITER(0, 8)    // s1m1 s2m2 = 8
    ITER(1, 10)   // s2m2 4 + st0 2 + s3m3 4 = 10
    ITER(2, 12)   // st0 + s3m3 + st1 + s4m4 = 12
    ITER(3, 12)   // st1 + s4m4 + st2 + s5m5 = 12
    ITER(4, 12)   // st2 + s5m5 + st3 + s6m6 = 12
    ITER_TAIL(5, 12)  // st3 + s6m6 + st4 + s7m7 = 12
    ITER_TAIL(6, 8)   // st4 + s7m7 + st5 = 8
    ITER_TAIL(7, 4)   // st5 + st6 = 4
}

extern "C" void kernel_launch(void* const* d_in, const int* in_sizes, int n_in,
                              void* d_out, int out_size, void* d_ws, size_t ws_size,
                              hipStream_t stream) {
    const float* x   = (const float*)d_in[0];
    const float* W   = (const float*)d_in[1];
    const int*   mod = (const int*)d_in[2];
    float*       out = (float*)d_out;

    const int n      = in_sizes[0] / HID;     // tokens (1<<20)
    const int blocks = n / (64 * GPB);        // 2048

    moe_qb<<<blocks, BLOCK, 0, stream>>>(x, W, mod, out);
}